// Round 18
// baseline (291.804 us; speedup 1.0000x reference)
//
#include <hip/hip_runtime.h>
#include <hip/hip_bf16.h>

// N=50000 nodes, E=800000 edges, D_IN=500, D_POS=2, LATENT=128, C=10
#define NEG_SLOPE 0.2f

typedef _Float16 half8   __attribute__((ext_vector_type(8)));
typedef _Float16 half2v  __attribute__((ext_vector_type(2)));
typedef _Float16 half4v  __attribute__((ext_vector_type(4)));
typedef float    float4v __attribute__((ext_vector_type(4)));

// async global->LDS 16B per lane (dest = wave-uniform base + lane*16)
__device__ __forceinline__ void gload16(const _Float16* g, _Float16* l)
{
    __builtin_amdgcn_global_load_lds(
        (const __attribute__((address_space(1))) unsigned int*)g,
        (__attribute__((address_space(3))) unsigned int*)l, 16, 0, 0);
}

// ---------------------------------------------------------------------------
// Edge count + rank (atomics isolated in their own kernel: R17 lesson —
// co-running 800k atomic RMWs with the concat stream serialized L2 and
// dropped the combined kernel to 26% of achievable BW)
// ---------------------------------------------------------------------------
__global__ __launch_bounds__(256)
void count_rank_kernel(const int* __restrict__ dst, int* __restrict__ cnt,
                       int* __restrict__ rank, int E)
{
    int e = blockIdx.x * 256 + threadIdx.x;
    if (e < E) rank[e] = atomicAdd(&cnt[dst[e]], 1);
}

// ---------------------------------------------------------------------------
// Mega prep kernel (streaming only, no atomics):
//   blocks [0,2048)        : concat(x,pos) -> f16 A0 [N x 512], float4 loads
//   blocks [2048,2304)     : W1 -> W1t   (502x512 -> 512x512 f16 T, pad)
//   blocks [2304,2432)     : W2 -> W2t   (512x256 -> 256x512 f16 T)
//   blocks [2432,2440)     : Wd1 -> Wd1t (128x64  -> 64x128 f16 T)
//   blocks [2440,2696)     : wfold: Wct = (W3 @ [Wl|Wr])^T f16 [256x256]
//   block  2696            : bfold: bcombo = b3@[Wl|Wr] + [bl|br]
// ---------------------------------------------------------------------------
__global__ __launch_bounds__(256)
void prep_mega_kernel(const float* __restrict__ x, const float* __restrict__ pos,
                      _Float16* __restrict__ A0,
                      const float* __restrict__ W1, _Float16* __restrict__ W1t,
                      const float* __restrict__ W2, _Float16* __restrict__ W2t,
                      const float* __restrict__ Wd1, _Float16* __restrict__ Wd1t,
                      const float* __restrict__ W3, const float* __restrict__ Wl,
                      const float* __restrict__ Wr, _Float16* __restrict__ Wct,
                      const float* __restrict__ b3, const float* __restrict__ bl,
                      const float* __restrict__ br, float* __restrict__ bcombo,
                      int N)
{
    const int b = blockIdx.x;
    const int t = threadIdx.x;

    if (b < 2048) {                      // ---- concat -> f16, 16B/lane loads
        const int total = N * 128;       // each item: 4 consecutive cols
        for (int i = b * 256 + t; i < total; i += 2048 * 256) {
            int node = i >> 7;
            int c4   = (i & 127) * 4;
            float4 v = make_float4(0.f, 0.f, 0.f, 0.f);
            if (c4 < 500)       v = *(const float4*)(x + (size_t)node * 500 + c4);
            else if (c4 == 500) { float2 p = *(const float2*)(pos + (size_t)node * 2);
                                  v.x = p.x; v.y = p.y; }
            half4v h;
            h[0] = (_Float16)v.x; h[1] = (_Float16)v.y;
            h[2] = (_Float16)v.z; h[3] = (_Float16)v.w;
            *(half4v*)(A0 + (size_t)node * 512 + c4) = h;
        }
    } else if (b < 2304) {               // ---- W1 transpose (pad k>=502)
        int bb = b - 2048;
        for (int i = bb * 256 + t; i < 512 * 512; i += 256 * 256) {
            int n = i >> 9, k = i & 511;
            W1t[i] = (_Float16)((k < 502) ? W1[(size_t)k * 512 + n] : 0.f);
        }
    } else if (b < 2432) {               // ---- W2 transpose (K=512 exact)
        int bb = b - 2304;
        for (int i = bb * 256 + t; i < 256 * 512; i += 128 * 256) {
            int n = i >> 9, k = i & 511;
            W2t[i] = (_Float16)W2[(size_t)k * 256 + n];
        }
    } else if (b < 2440) {               // ---- Wd1 transpose (K=128 exact)
        int bb = b - 2432;
        for (int i = bb * 256 + t; i < 64 * 128; i += 8 * 256) {
            int n = i >> 7, k = i & 127;
            Wd1t[i] = (_Float16)Wd1[(size_t)k * 64 + n];
        }
    } else if (b < 2696) {               // ---- wfold
        __shared__ float colv[128];
        int nn = b - 2440;
        const float* Ws = (nn < 128) ? Wl : Wr;
        int c = nn & 127;
        if (t < 128) colv[t] = Ws[t * 128 + c];
        __syncthreads();
        const float* wrow = W3 + t * 128;
        float s = 0.f;
        #pragma unroll 8
        for (int j = 0; j < 128; ++j) s += wrow[j] * colv[j];
        Wct[nn * 256 + t] = (_Float16)s;
    } else {                             // ---- bfold
        int nn = t;
        const float* Ws = (nn < 128) ? Wl : Wr;
        int c = nn & 127;
        float s = (nn < 128) ? bl[c] : br[c];
        for (int j = 0; j < 128; ++j) s += b3[j] * Ws[j * 128 + c];
        bcombo[nn] = s;
    }
}

// ---------------------------------------------------------------------------
// Atomic-free edge scatter: slot = row_start[dst] + precomputed rank.
// ---------------------------------------------------------------------------
__global__ __launch_bounds__(256)
void scatter_kernel(const int* __restrict__ dst, const int* __restrict__ src,
                    const float* __restrict__ ea, const int* __restrict__ row_start,
                    const int* __restrict__ rank, int2* __restrict__ recs, int E)
{
    int e = blockIdx.x * 256 + threadIdx.x;
    if (e < E) {
        int p = row_start[dst[e]] + rank[e];
        recs[p] = make_int2(src[e], __float_as_int(ea[e]));
    }
}

// ---------------------------------------------------------------------------
// XCD-aware bijective swizzle (m204)
// ---------------------------------------------------------------------------
__device__ inline void decode_swz(int b, int nblk, int ny, int& bx, int& by)
{
    int q = nblk >> 3, r = nblk & 7;
    int xcd = b & 7, j = b >> 3;
    int L = (xcd < r ? xcd * (q + 1) : r * (q + 1) + (xcd - r) * q) + j;
    bx = L / ny;
    by = L - bx * ny;
}

// ---------------------------------------------------------------------------
// f16 MFMA GEMM: 128x128 block, BK=32, 4 waves (2x2), wave 64x64 via 4x4
// mfma_f32_16x16x32_f16. global_load_lds staging, 3-deep LDS pipeline with
// counted vmcnt + raw s_barrier. XOR chunk swizzle both sides (G21).
// ---------------------------------------------------------------------------
template<int WF32, int WF16>
__global__ __launch_bounds__(256)
void gemm_f16_kernel(const _Float16* __restrict__ A, const _Float16* __restrict__ Bt,
                     const float* __restrict__ bias, float* __restrict__ Cf,
                     _Float16* __restrict__ Ch, int M, int N, int K, int ny, int do_relu)
{
    __shared__ __align__(16) _Float16 smem[3][8192];   // 3 x (A 8KB + B 8KB)

    int bx, by;
    decode_swz(blockIdx.x, gridDim.x, ny, bx, by);

    const int t    = threadIdx.x;
    const int row0 = bx * 128;
    const int n0   = by * 128;
    const int lane = t & 63;
    const int w    = t >> 6;
    const int wrow = (w >> 1) * 64;
    const int wcol = (w & 1) * 64;
    const int lrow = lane & 15;
    const int lk   = lane >> 4;
    const int sw   = lk ^ ((lrow >> 1) & 3);      // read-side chunk swizzle

    const int rl     = lane >> 2;
    const int lk_log = (lane & 3) ^ ((lane >> 3) & 3);

    int rA0 = row0 + w * 16 + rl;        if (rA0 > M - 1) rA0 = M - 1;
    int rA1 = row0 + (w + 4) * 16 + rl;  if (rA1 > M - 1) rA1 = M - 1;
    int rB0 = n0 + w * 16 + rl;          if (rB0 > N - 1) rB0 = N - 1;
    int rB1 = n0 + (w + 4) * 16 + rl;    if (rB1 > N - 1) rB1 = N - 1;

    const _Float16* gA0 = A  + (size_t)rA0 * K + lk_log * 8;
    const _Float16* gA1 = A  + (size_t)rA1 * K + lk_log * 8;
    const _Float16* gB0 = Bt + (size_t)rB0 * K + lk_log * 8;
    const _Float16* gB1 = Bt + (size_t)rB1 * K + lk_log * 8;

    float4v acc[4][4];
    #pragma unroll
    for (int i = 0; i < 4; ++i)
        #pragma unroll
        for (int j = 0; j < 4; ++j)
            acc[i][j] = (float4v){0.f, 0.f, 0.f, 0.f};

    const int KT = K >> 5;

    auto stage = [&](int kt, int buf) {
        _Float16* sA = &smem[buf][0];
        _Float16* sB = &smem[buf][4096];
        int ko = kt * 32;
        gload16(gA0 + ko, sA + (w    ) * 512);
        gload16(gA1 + ko, sA + (w + 4) * 512);
        gload16(gB0 + ko, sB + (w    ) * 512);
        gload16(gB1 + ko, sB + (w + 4) * 512);
    };

    stage(0, 0);
    if (KT > 1) {
        stage(1, 1);
        asm volatile("s_waitcnt vmcnt(4)" ::: "memory");
    } else {
        asm volatile("s_waitcnt vmcnt(0)" ::: "memory");
    }
    __builtin_amdgcn_sched_barrier(0);
    __builtin_amdgcn_s_barrier();

    for (int kt = 0; kt < KT; ++kt) {
        if (kt + 2 < KT) stage(kt + 2, (kt + 2) % 3);

        const _Float16* bufA = &smem[kt % 3][0];
        const _Float16* bufB = &smem[kt % 3][4096];

        half8 af[4], bf[4];
        #pragma unroll
        for (int mi = 0; mi < 4; ++mi)
            af[mi] = *(const half8*)(bufA + (wrow + mi * 16 + lrow) * 32 + sw * 8);
        #pragma unroll
        for (int ni = 0; ni < 4; ++ni)
            bf[ni] = *(const half8*)(bufB + (wcol + ni * 16 + lrow) * 32 + sw * 8);

        #pragma unroll
        for (int mi = 0; mi < 4; ++mi)
            #pragma unroll
            for (int ni = 0; ni < 4; ++ni)
                acc[mi][ni] = __builtin_amdgcn_mfma_f32_16x16x32_f16(
                    af[mi], bf[ni], acc[mi][ni], 0, 0, 0);

        if (kt + 1 < KT) {
            if (kt + 2 < KT) asm volatile("s_waitcnt vmcnt(4)" ::: "memory");
            else             asm volatile("s_waitcnt vmcnt(0)" ::: "memory");
            __builtin_amdgcn_sched_barrier(0);
            __builtin_amdgcn_s_barrier();
        }
    }

    #pragma unroll
    for (int mi = 0; mi < 4; ++mi) {
        #pragma unroll
        for (int ni = 0; ni < 4; ++ni) {
            #pragma unroll
            for (int r = 0; r < 4; ++r) {
                int row = row0 + wrow + mi * 16 + lk * 4 + r;
                int col = n0 + wcol + ni * 16 + lrow;
                if (row < M && col < N) {
                    float v = acc[mi][ni][r] + bias[col];
                    if (do_relu) v = fmaxf(v, 0.f);
                    if (WF32) Cf[(size_t)row * N + col] = v;
                    if (WF16) Ch[(size_t)row * N + col] = (_Float16)v;
                }
            }
        }
    }
}

// ---------------------------------------------------------------------------
// Fused decoder: d = relu(z @ Wd1 + bd1); logits = d @ Wd2 + bd2; softmax.
// ---------------------------------------------------------------------------
__global__ __launch_bounds__(256)
void dec_fused_kernel(const _Float16* __restrict__ zh, const _Float16* __restrict__ Wd1t,
                      const float* __restrict__ bd1, const float* __restrict__ Wd2,
                      const float* __restrict__ bd2, float* __restrict__ out, int n)
{
    __shared__ __align__(16) _Float16 zs[128 * 40];
    __shared__ __align__(16) _Float16 wd1s[64 * 136];
    __shared__ __align__(16) _Float16 dsd[128 * 66];
    __shared__ float wd2s[640];
    __shared__ float bd1s[64];
    __shared__ float bd2s[10];

    const int t    = threadIdx.x;
    const int lane = t & 63;
    const int w    = t >> 6;
    const int wrow = (w >> 1) * 64;
    const int wcol = (w & 1) * 32;
    const int lrow = lane & 15;
    const int lk   = lane >> 4;
    const int node0 = blockIdx.x * 128;

    for (int i = t; i < 64 * 16; i += 256) {
        int r = i >> 4, c8 = i & 15;
        *(half8*)&wd1s[r * 136 + c8 * 8] = *(const half8*)(Wd1t + r * 128 + c8 * 8);
    }
    for (int i = t; i < 640; i += 256) wd2s[i] = Wd2[i];
    if (t < 64) bd1s[t] = bd1[t];
    if (t < 10) bd2s[t] = bd2[t];

    float4v acc[4][2];
    #pragma unroll
    for (int i = 0; i < 4; ++i)
        #pragma unroll
        for (int j = 0; j < 2; ++j)
            acc[i][j] = (float4v){0.f, 0.f, 0.f, 0.f};

    const int zrow = t >> 1;
    const int ch   = t & 1;
    int gz = node0 + zrow; if (gz > n - 1) gz = n - 1;
    const _Float16* zsrc = zh + (size_t)gz * 128 + ch * 16;

    for (int kt = 0; kt < 4; ++kt) {
        __syncthreads();
        *(half8*)&zs[zrow * 40 + ch * 16]     = *(const half8*)(zsrc + kt * 32);
        *(half8*)&zs[zrow * 40 + ch * 16 + 8] = *(const half8*)(zsrc + kt * 32 + 8);
        __syncthreads();

        half8 af[4], bf[2];
        #pragma unroll
        for (int mi = 0; mi < 4; ++mi)
            af[mi] = *(const half8*)&zs[(wrow + mi * 16 + lrow) * 40 + lk * 8];
        #pragma unroll
        for (int ni = 0; ni < 2; ++ni)
            bf[ni] = *(const half8*)&wd1s[(wcol + ni * 16 + lrow) * 136 + kt * 32 + lk * 8];

        #pragma unroll
        for (int mi = 0; mi < 4; ++mi)
            #pragma unroll
            for (int ni = 0; ni < 2; ++ni)
                acc[mi][ni] = __builtin_amdgcn_mfma_f32_16x16x32_f16(
                    af[mi], bf[ni], acc[mi][ni], 0, 0, 0);
    }

    #pragma unroll
    for (int mi = 0; mi < 4; ++mi) {
        #pragma unroll
        for (int ni = 0; ni < 2; ++ni) {
            #pragma unroll
            for (int r = 0; r < 4; ++r) {
                int rr = wrow + mi * 16 + lk * 4 + r;
                int cc = wcol + ni * 16 + lrow;
                float v = fmaxf(acc[mi][ni][r] + bd1s[cc], 0.f);
                dsd[rr * 66 + cc] = (_Float16)v;
            }
        }
    }
    __syncthreads();

    if (t < 128) {
        int node = node0 + t;
        if (node < n) {
            float lg[10];
            #pragma unroll
            for (int c = 0; c < 10; ++c) lg[c] = bd2s[c];
            #pragma unroll
            for (int k8 = 0; k8 < 8; ++k8) {
                half8 dv = *(const half8*)&dsd[t * 66 + k8 * 8];
                #pragma unroll
                for (int j = 0; j < 8; ++j) {
                    float dj = (float)dv[j];
                    #pragma unroll
                    for (int c = 0; c < 10; ++c)
                        lg[c] += dj * wd2s[(k8 * 8 + j) * 10 + c];
                }
            }
            float mx = lg[0];
            #pragma unroll
            for (int c = 1; c < 10; ++c) mx = fmaxf(mx, lg[c]);
            float ssum = 0.f;
            #pragma unroll
            for (int c = 0; c < 10; ++c) { lg[c] = expf(lg[c] - mx); ssum += lg[c]; }
            float inv = 1.f / ssum;
            #pragma unroll
            for (int c = 0; c < 10; ++c)
                out[(size_t)node * 10 + c] = lg[c] * inv;
        }
    }
}

// ---------------------------------------------------------------------------
// CSR scan
// ---------------------------------------------------------------------------
__global__ __launch_bounds__(256)
void block_sum_kernel(const int* __restrict__ cnt, int* __restrict__ bsum, int n)
{
    __shared__ int sh[256];
    int t = threadIdx.x;
    int i = blockIdx.x * 256 + t;
    sh[t] = (i < n) ? cnt[i] : 0;
    __syncthreads();
    #pragma unroll
    for (int off = 128; off > 0; off >>= 1) {
        if (t < off) sh[t] += sh[t + off];
        __syncthreads();
    }
    if (t == 0) bsum[blockIdx.x] = sh[0];
}

__global__ __launch_bounds__(256)
void scan_bsum_kernel(int* __restrict__ bsum, int* __restrict__ row_start, int nb, int n)
{
    __shared__ int sh[256];
    int t = threadIdx.x;
    int v = (t < nb) ? bsum[t] : 0;
    sh[t] = v;
    __syncthreads();
    #pragma unroll
    for (int off = 1; off < 256; off <<= 1) {
        int xv = (t >= off) ? sh[t - off] : 0;
        __syncthreads();
        sh[t] += xv;
        __syncthreads();
    }
    if (t < nb) bsum[t] = sh[t] - v;
    if (t == 255) row_start[n] = sh[255];
}

__global__ __launch_bounds__(256)
void scan_final_kernel(const int* __restrict__ cnt, const int* __restrict__ boff,
                       int* __restrict__ row_start, int n)
{
    __shared__ int sh[256];
    int t = threadIdx.x;
    int i = blockIdx.x * 256 + t;
    int v = (i < n) ? cnt[i] : 0;
    sh[t] = v;
    __syncthreads();
    #pragma unroll
    for (int off = 1; off < 256; off <<= 1) {
        int xv = (t >= off) ? sh[t - off] : 0;
        __syncthreads();
        sh[t] += xv;
        __syncthreads();
    }
    if (i < n) row_start[i] = boff[blockIdx.x] + sh[t] - v;
}

// ---------------------------------------------------------------------------
// Fused GATv2: one wave per dst node; 4x16-lane groups, 4 edges in flight.
// Packed-f16 message math + fdot2 logit; defer-max online softmax (THR=8).
// ---------------------------------------------------------------------------
__global__ __launch_bounds__(256)
void gat_aggregate_kernel(const _Float16* __restrict__ xlr, const int2* __restrict__ recs,
                          const float* __restrict__ We, const float* __restrict__ att,
                          const float* __restrict__ bg, const int* __restrict__ row_start,
                          _Float16* __restrict__ z, int n)
{
    const int wave = threadIdx.x >> 6;
    const int lane = threadIdx.x & 63;
    const int node = blockIdx.x * 4 + wave;
    if (node >= n) return;

    const int g  = lane >> 4;
    const int sl = lane & 15;
    const int d0 = sl * 8;

    half2v at_h[4], we_h[4], xr_h[4];
    {
        float4 a0 = *(const float4*)(att + d0);
        float4 a1 = *(const float4*)(att + d0 + 4);
        float4 w0 = *(const float4*)(We + d0);
        float4 w1 = *(const float4*)(We + d0 + 4);
        at_h[0] = (half2v){(_Float16)a0.x, (_Float16)a0.y};
        at_h[1] = (half2v){(_Float16)a0.z, (_Float16)a0.w};
        at_h[2] = (half2v){(_Float16)a1.x, (_Float16)a1.y};
        at_h[3] = (half2v){(_Float16)a1.z, (_Float16)a1.w};
        we_h[0] = (half2v){(_Float16)w0.x, (_Float16)w0.y};
        we_h[1] = (half2v){(_Float16)w0.z, (_Float16)w0.w};
        we_h[2] = (half2v){(_Float16)w1.x, (_Float16)w1.y};
        we_h[3] = (half2v){(_Float16)w1.z, (_Float16)w1.w};
        half8 xh = *(const half8*)(xlr + (size_t)node * 256 + 128 + d0);
        #pragma unroll
        for (int q = 0; q < 4; ++q)
            xr_h[q] = (half2v){xh[2 * q], xh[2 * q + 1]};
    }
    const half2v slope2 = (half2v){(_Float16)NEG_SLOPE, (_Float16)NEG_SLOPE};

    const int beg = row_start[node];
    const int end = row_start[node + 1];

    float m_run = -INFINITY;
    float l_run = 0.f;
    float acc[8];
    #pragma unroll
    for (int j = 0; j < 8; ++j) acc[j] = 0.f;

    for (int idx = beg + g; idx < end; idx += 4) {
        int2 rec = recs[idx];
        _Float16 eh = (_Float16)__int_as_float(rec.y);
        half2v e2 = (half2v){eh, eh};
        half8 xh = *(const half8*)(xlr + (size_t)rec.x * 256 + d0);

        float part = 0.f;
        #pragma unroll
        for (int q = 0; q < 4; ++q) {
            half2v xq = (half2v){xh[2 * q], xh[2 * q + 1]};
            half2v mq = xq + (e2 * we_h[q] + xr_h[q]);
            half2v lq = __builtin_elementwise_max(mq, mq * slope2);
#if __has_builtin(__builtin_amdgcn_fdot2)
            part = __builtin_amdgcn_fdot2(lq, at_h[q], part, false);
#else
            part += (float)lq.x * (float)at_h[q].x + (float)lq.y * (float)at_h[q].y;
#endif
        }
        part += __shfl_xor(part, 1);
        part += __shfl_xor(part, 2);
        part += __shfl_xor(part, 4);
        part += __shfl_xor(part, 8);

        if (part <= m_run + 8.f) {
            float p = __expf(part - m_run);
            l_run += p;
            #pragma unroll
            for (int j = 0; j < 8; ++j) acc[j] += p * (float)xh[j];
        } else {
            float sc = __expf(m_run - part);
            l_run = l_run * sc + 1.f;
            #pragma unroll
            for (int j = 0; j < 8; ++j) acc[j] = acc[j] * sc + (float)xh[j];
            m_run = part;
        }
    }

    #pragma unroll
    for (int off = 16; off <= 32; off <<= 1) {
        float m_o = __shfl_xor(m_run, off);
        float l_o = __shfl_xor(l_run, off);
        float mn  = fmaxf(m_run, m_o);
        float sa  = (m_run == mn) ? 1.f : __expf(m_run - mn);
        float sb  = (m_o   == mn) ? 1.f : __expf(m_o - mn);
        l_run = l_run * sa + l_o * sb;
        #pragma unroll
        for (int j = 0; j < 8; ++j) {
            float a_o = __shfl_xor(acc[j], off);
            acc[j] = acc[j] * sa + a_o * sb;
        }
        m_run = mn;
    }

    if (g == 0) {
        float inv = (l_run > 0.f) ? 1.f / l_run : 0.f;
        const float* bgp = bg + d0;
        half8 o;
        #pragma unroll
        for (int j = 0; j < 8; ++j) {
            float v = fmaxf(acc[j] * inv + bgp[j], 0.f);
            o[j] = (_Float16)v;
        }
        *(half8*)(z + (size_t)node * 128 + d0) = o;
    }
}

// ---------------------------------------------------------------------------
// Launch
// ---------------------------------------------------------------------------
extern "C" void kernel_launch(void* const* d_in, const int* in_sizes, int n_in,
                              void* d_out, int out_size, void* d_ws, size_t ws_size,
                              hipStream_t stream)
{
    const float* x    = (const float*)d_in[0];
    const float* pos  = (const float*)d_in[1];
    const int*   ei   = (const int*)d_in[2];
    const float* ea   = (const float*)d_in[3];
    const float* W1   = (const float*)d_in[4];
    const float* b1   = (const float*)d_in[5];
    const float* W2   = (const float*)d_in[6];
    const float* b2   = (const float*)d_in[7];
    const float* W3   = (const float*)d_in[8];
    const float* b3   = (const float*)d_in[9];
    const float* Wl   = (const float*)d_in[10];
    const float* bl   = (const float*)d_in[11];
    const float* Wr   = (const float*)d_in[12];
    const float* br   = (const float*)d_in[13];
    const float* We   = (const float*)d_in[14];
    const float* att  = (const float*)d_in[15];
    const float* bg   = (const float*)d_in[16];
    const float* Wd1  = (const float*)d_in[17];
    const float* bd1  = (const float*)d_in[18];
    const float* Wd2  = (const float*)d_in[19];
    const float* bd2  = (const float*)d_in[20];
    float* out = (float*)d_out;

    const int N = in_sizes[0] / 500;   // 50000
    const int E = in_sizes[2] / 2;     // 800000

    // ---- workspace layout (bytes) ----
    char* base = (char*)d_ws;
    const size_t szR = (size_t)N * 512 * 2;   // 51.2 MB region size
    _Float16* A0h = (_Float16*)(base);                            // N*512 f16
    _Float16* h2h = (_Float16*)(base);                            // N*256 f16 (A0h dead)
    _Float16* zh  = (_Float16*)(base + (size_t)N * 384 * 2);      // N*128 f16
    char* r1 = base + szR;
    _Float16* h1h = (_Float16*)(r1);                              // N*512 f16
    _Float16* xlr = (_Float16*)(r1);                              // N*256 f16 (h1h dead)
    char* r2 = base + 2 * szR;
    _Float16* W1t   = (_Float16*)(r2);                // 512*512
    _Float16* W2t   = W1t  + 512 * 512;               // 256*512
    _Float16* Wct   = W2t  + 256 * 512;               // 256*256 (folded W3@[Wl|Wr])
    _Float16* Wd1t  = Wct  + 256 * 256;               // 64*128
    float*    bcombo = (float*)(Wd1t + 64 * 128);     // 256 f32
    int* cnt       = (int*)(r2 + 2 * 1024 * 1024);
    int* row_start = cnt + N;
    int* bsum      = row_start + N + 1;
    int2* recs     = (int2*)(r2 + 3 * 1024 * 1024);   // E * 8 bytes
    int* rank      = (int*)(recs + E);                // E ints

    const int* srcArr = ei;
    const int* dstArr = ei + E;
    const int gx = (N + 127) / 128;                   // 391 row-blocks
    const int nb = (N + 255) / 256;                   // 196
    const int eb = (E + 255) / 256;                   // 3125

    // ---- edge count+rank (atomics isolated) ----
    hipMemsetAsync(cnt, 0, (size_t)N * sizeof(int), stream);
    count_rank_kernel<<<eb, 256, 0, stream>>>(dstArr, cnt, rank, E);

    // ---- streaming prep: concat + weight converts + folds ----
    prep_mega_kernel<<<2697, 256, 0, stream>>>(
        x, pos, A0h, W1, W1t, W2, W2t, Wd1, Wd1t,
        W3, Wl, Wr, Wct, b3, bl, br, bcombo, N);

    // ---- CSR scan + atomic-free scatter ----
    block_sum_kernel<<<nb, 256, 0, stream>>>(cnt, bsum, N);
    scan_bsum_kernel<<<1, 256, 0, stream>>>(bsum, row_start, nb, N);
    scan_final_kernel<<<nb, 256, 0, stream>>>(cnt, bsum, row_start, N);
    scatter_kernel<<<eb, 256, 0, stream>>>(dstArr, srcArr, ea, row_start, rank, recs, E);

    // ---- encoder ----
    gemm_f16_kernel<0,1><<<gx * 4, 256, 0, stream>>>(A0h, W1t, b1, nullptr, h1h, N, 512, 512, 4, 1);
    gemm_f16_kernel<0,1><<<gx * 2, 256, 0, stream>>>(h1h, W2t, b2, nullptr, h2h, N, 256, 512, 2, 1);
    // ---- folded h->xl|xr transform: xlr = h2 @ Wcombo + bcombo ----
    gemm_f16_kernel<0,1><<<gx * 2, 256, 0, stream>>>(h2h, Wct, bcombo, nullptr, xlr, N, 256, 256, 2, 0);

    // ---- fused GATv2 softmax + aggregation ----
    gat_aggregate_kernel<<<(N + 3) / 4, 256, 0, stream>>>(xlr, recs, We, att, bg,
                                                          row_start, zh, N);

    // ---- fused decoder (dec1 + dec2 + softmax) ----
    dec_fused_kernel<<<gx, 256, 0, stream>>>(zh, Wd1t, bd1, Wd2, bd2, out, N);
}

// Round 19
// 277.123 us; speedup vs baseline: 1.0530x; 1.0530x over previous
//
#include <hip/hip_runtime.h>
#include <hip/hip_bf16.h>

// N=50000 nodes, E=800000 edges, D_IN=500, D_POS=2, LATENT=128, C=10
#define NEG_SLOPE 0.2f

typedef _Float16 half8   __attribute__((ext_vector_type(8)));
typedef _Float16 half2v  __attribute__((ext_vector_type(2)));
typedef _Float16 half4v  __attribute__((ext_vector_type(4)));
typedef float    float4v __attribute__((ext_vector_type(4)));

// async global->LDS 16B per lane (dest = wave-uniform base + lane*16)
__device__ __forceinline__ void gload16(const _Float16* g, _Float16* l)
{
    __builtin_amdgcn_global_load_lds(
        (const __attribute__((address_space(1))) unsigned int*)g,
        (__attribute__((address_space(3))) unsigned int*)l, 16, 0, 0);
}

// ---------------------------------------------------------------------------
// Mega prep kernel: all independent prep work in ONE launch (R18 lesson:
// keeping the atomic count co-resident with the streaming work HIDES its
// latency; splitting it out costs ~10us).
//   blocks [0,2048)    : concat(x,pos) -> f16 A0 [N x 512], float4 loads
//   blocks [2048,2304) : W1 -> W1t, [2304,2432): W2 -> W2t, [2432,2440): Wd1
//   blocks [2440,2696) : wfold; block 2696: bfold
//   blocks [2697,...)  : count_edges + per-edge rank (cnt pre-zeroed)
// ---------------------------------------------------------------------------
__global__ __launch_bounds__(256)
void prep_mega_kernel(const float* __restrict__ x, const float* __restrict__ pos,
                      _Float16* __restrict__ A0,
                      const float* __restrict__ W1, _Float16* __restrict__ W1t,
                      const float* __restrict__ W2, _Float16* __restrict__ W2t,
                      const float* __restrict__ Wd1, _Float16* __restrict__ Wd1t,
                      const float* __restrict__ W3, const float* __restrict__ Wl,
                      const float* __restrict__ Wr, _Float16* __restrict__ Wct,
                      const float* __restrict__ b3, const float* __restrict__ bl,
                      const float* __restrict__ br, float* __restrict__ bcombo,
                      const int* __restrict__ dstA, int* __restrict__ cnt,
                      int* __restrict__ rank, int N, int E)
{
    const int b = blockIdx.x;
    const int t = threadIdx.x;

    if (b < 2048) {                      // ---- concat -> f16 (float4 loads)
        const int total = N * 128;       // each item: 4 consecutive cols
        for (int i = b * 256 + t; i < total; i += 2048 * 256) {
            int node = i >> 7;
            int c4   = (i & 127) * 4;
            float4 v = make_float4(0.f, 0.f, 0.f, 0.f);
            if (c4 < 500)       v = *(const float4*)(x + (size_t)node * 500 + c4);
            else if (c4 == 500) { float2 p = *(const float2*)(pos + (size_t)node * 2);
                                  v.x = p.x; v.y = p.y; }
            half4v h;
            h[0] = (_Float16)v.x; h[1] = (_Float16)v.y;
            h[2] = (_Float16)v.z; h[3] = (_Float16)v.w;
            *(half4v*)(A0 + (size_t)node * 512 + c4) = h;
        }
    } else if (b < 2304) {               // ---- W1 transpose (pad k>=502)
        int bb = b - 2048;
        for (int i = bb * 256 + t; i < 512 * 512; i += 256 * 256) {
            int n = i >> 9, k = i & 511;
            W1t[i] = (_Float16)((k < 502) ? W1[(size_t)k * 512 + n] : 0.f);
        }
    } else if (b < 2432) {               // ---- W2 transpose (K=512 exact)
        int bb = b - 2304;
        for (int i = bb * 256 + t; i < 256 * 512; i += 128 * 256) {
            int n = i >> 9, k = i & 511;
            W2t[i] = (_Float16)W2[(size_t)k * 256 + n];
        }
    } else if (b < 2440) {               // ---- Wd1 transpose (K=128 exact)
        int bb = b - 2432;
        for (int i = bb * 256 + t; i < 64 * 128; i += 8 * 256) {
            int n = i >> 7, k = i & 127;
            Wd1t[i] = (_Float16)Wd1[(size_t)k * 64 + n];
        }
    } else if (b < 2696) {               // ---- wfold
        __shared__ float colv[128];
        int nn = b - 2440;
        const float* Ws = (nn < 128) ? Wl : Wr;
        int c = nn & 127;
        if (t < 128) colv[t] = Ws[t * 128 + c];
        __syncthreads();
        const float* wrow = W3 + t * 128;
        float s = 0.f;
        #pragma unroll 8
        for (int j = 0; j < 128; ++j) s += wrow[j] * colv[j];
        Wct[nn * 256 + t] = (_Float16)s;
    } else if (b == 2696) {              // ---- bfold
        int nn = t;
        const float* Ws = (nn < 128) ? Wl : Wr;
        int c = nn & 127;
        float s = (nn < 128) ? bl[c] : br[c];
        for (int j = 0; j < 128; ++j) s += b3[j] * Ws[j * 128 + c];
        bcombo[nn] = s;
    } else {                             // ---- count_edges + rank
        int e = (b - 2697) * 256 + t;
        if (e < E) rank[e] = atomicAdd(&cnt[dstA[e]], 1);
    }
}

// ---------------------------------------------------------------------------
// XCD-aware bijective swizzle (m204)
// ---------------------------------------------------------------------------
__device__ inline void decode_swz(int b, int nblk, int ny, int& bx, int& by)
{
    int q = nblk >> 3, r = nblk & 7;
    int xcd = b & 7, j = b >> 3;
    int L = (xcd < r ? xcd * (q + 1) : r * (q + 1) + (xcd - r) * q) + j;
    bx = L / ny;
    by = L - bx * ny;
}

// ---------------------------------------------------------------------------
// f16 MFMA GEMM: 128x128 block, BK=32, 4 waves (2x2), wave 64x64 via 4x4
// mfma_f32_16x16x32_f16. global_load_lds staging, 3-deep LDS pipeline with
// counted vmcnt + raw s_barrier. XOR chunk swizzle both sides (G21).
// SCAT=1: each block scatters a contiguous edge slice after its epilogue
// using precomputed rank[] (atomic-free; best-measured placement, R16).
// ---------------------------------------------------------------------------
template<int WF32, int WF16, int SCAT>
__global__ __launch_bounds__(256)
void gemm_f16_kernel(const _Float16* __restrict__ A, const _Float16* __restrict__ Bt,
                     const float* __restrict__ bias, float* __restrict__ Cf,
                     _Float16* __restrict__ Ch, int M, int N, int K, int ny, int do_relu,
                     const int* __restrict__ s_dst, const int* __restrict__ s_src,
                     const float* __restrict__ s_ea, const int* __restrict__ s_rowstart,
                     const int* __restrict__ s_rank, int2* __restrict__ s_recs, int s_E)
{
    __shared__ __align__(16) _Float16 smem[3][8192];   // 3 x (A 8KB + B 8KB)

    int bx, by;
    decode_swz(blockIdx.x, gridDim.x, ny, bx, by);

    const int t    = threadIdx.x;
    const int row0 = bx * 128;
    const int n0   = by * 128;
    const int lane = t & 63;
    const int w    = t >> 6;
    const int wrow = (w >> 1) * 64;
    const int wcol = (w & 1) * 64;
    const int lrow = lane & 15;
    const int lk   = lane >> 4;
    const int sw   = lk ^ ((lrow >> 1) & 3);      // read-side chunk swizzle

    const int rl     = lane >> 2;
    const int lk_log = (lane & 3) ^ ((lane >> 3) & 3);

    int rA0 = row0 + w * 16 + rl;        if (rA0 > M - 1) rA0 = M - 1;
    int rA1 = row0 + (w + 4) * 16 + rl;  if (rA1 > M - 1) rA1 = M - 1;
    int rB0 = n0 + w * 16 + rl;          if (rB0 > N - 1) rB0 = N - 1;
    int rB1 = n0 + (w + 4) * 16 + rl;    if (rB1 > N - 1) rB1 = N - 1;

    const _Float16* gA0 = A  + (size_t)rA0 * K + lk_log * 8;
    const _Float16* gA1 = A  + (size_t)rA1 * K + lk_log * 8;
    const _Float16* gB0 = Bt + (size_t)rB0 * K + lk_log * 8;
    const _Float16* gB1 = Bt + (size_t)rB1 * K + lk_log * 8;

    float4v acc[4][4];
    #pragma unroll
    for (int i = 0; i < 4; ++i)
        #pragma unroll
        for (int j = 0; j < 4; ++j)
            acc[i][j] = (float4v){0.f, 0.f, 0.f, 0.f};

    const int KT = K >> 5;

    auto stage = [&](int kt, int buf) {
        _Float16* sA = &smem[buf][0];
        _Float16* sB = &smem[buf][4096];
        int ko = kt * 32;
        gload16(gA0 + ko, sA + (w    ) * 512);
        gload16(gA1 + ko, sA + (w + 4) * 512);
        gload16(gB0 + ko, sB + (w    ) * 512);
        gload16(gB1 + ko, sB + (w + 4) * 512);
    };

    stage(0, 0);
    if (KT > 1) {
        stage(1, 1);
        asm volatile("s_waitcnt vmcnt(4)" ::: "memory");
    } else {
        asm volatile("s_waitcnt vmcnt(0)" ::: "memory");
    }
    __builtin_amdgcn_sched_barrier(0);
    __builtin_amdgcn_s_barrier();

    for (int kt = 0; kt < KT; ++kt) {
        if (kt + 2 < KT) stage(kt + 2, (kt + 2) % 3);

        const _Float16* bufA = &smem[kt % 3][0];
        const _Float16* bufB = &smem[kt % 3][4096];

        half8 af[4], bf[4];
        #pragma unroll
        for (int mi = 0; mi < 4; ++mi)
            af[mi] = *(const half8*)(bufA + (wrow + mi * 16 + lrow) * 32 + sw * 8);
        #pragma unroll
        for (int ni = 0; ni < 4; ++ni)
            bf[ni] = *(const half8*)(bufB + (wcol + ni * 16 + lrow) * 32 + sw * 8);

        #pragma unroll
        for (int mi = 0; mi < 4; ++mi)
            #pragma unroll
            for (int ni = 0; ni < 4; ++ni)
                acc[mi][ni] = __builtin_amdgcn_mfma_f32_16x16x32_f16(
                    af[mi], bf[ni], acc[mi][ni], 0, 0, 0);

        if (kt + 1 < KT) {
            if (kt + 2 < KT) asm volatile("s_waitcnt vmcnt(4)" ::: "memory");
            else             asm volatile("s_waitcnt vmcnt(0)" ::: "memory");
            __builtin_amdgcn_sched_barrier(0);
            __builtin_amdgcn_s_barrier();
        }
    }

    #pragma unroll
    for (int mi = 0; mi < 4; ++mi) {
        #pragma unroll
        for (int ni = 0; ni < 4; ++ni) {
            #pragma unroll
            for (int r = 0; r < 4; ++r) {
                int row = row0 + wrow + mi * 16 + lk * 4 + r;
                int col = n0 + wcol + ni * 16 + lrow;
                if (row < M && col < N) {
                    float v = acc[mi][ni][r] + bias[col];
                    if (do_relu) v = fmaxf(v, 0.f);
                    if (WF32) Cf[(size_t)row * N + col] = v;
                    if (WF16) Ch[(size_t)row * N + col] = (_Float16)v;
                }
            }
        }
    }

    if (SCAT) {
        // atomic-free scatter: slot = row_start[dst] + precomputed rank
        int epb = (s_E + gridDim.x - 1) / gridDim.x;
        int e0  = blockIdx.x * epb;
        int e1  = e0 + epb; if (e1 > s_E) e1 = s_E;
        for (int e = e0 + t; e < e1; e += 256) {
            int p = s_rowstart[s_dst[e]] + s_rank[e];
            s_recs[p] = make_int2(s_src[e], __float_as_int(s_ea[e]));
        }
    }
}

// ---------------------------------------------------------------------------
// Fused decoder: d = relu(z @ Wd1 + bd1); logits = d @ Wd2 + bd2; softmax.
// ---------------------------------------------------------------------------
__global__ __launch_bounds__(256)
void dec_fused_kernel(const _Float16* __restrict__ zh, const _Float16* __restrict__ Wd1t,
                      const float* __restrict__ bd1, const float* __restrict__ Wd2,
                      const float* __restrict__ bd2, float* __restrict__ out, int n)
{
    __shared__ __align__(16) _Float16 zs[128 * 40];
    __shared__ __align__(16) _Float16 wd1s[64 * 136];
    __shared__ __align__(16) _Float16 dsd[128 * 66];
    __shared__ float wd2s[640];
    __shared__ float bd1s[64];
    __shared__ float bd2s[10];

    const int t    = threadIdx.x;
    const int lane = t & 63;
    const int w    = t >> 6;
    const int wrow = (w >> 1) * 64;
    const int wcol = (w & 1) * 32;
    const int lrow = lane & 15;
    const int lk   = lane >> 4;
    const int node0 = blockIdx.x * 128;

    for (int i = t; i < 64 * 16; i += 256) {
        int r = i >> 4, c8 = i & 15;
        *(half8*)&wd1s[r * 136 + c8 * 8] = *(const half8*)(Wd1t + r * 128 + c8 * 8);
    }
    for (int i = t; i < 640; i += 256) wd2s[i] = Wd2[i];
    if (t < 64) bd1s[t] = bd1[t];
    if (t < 10) bd2s[t] = bd2[t];

    float4v acc[4][2];
    #pragma unroll
    for (int i = 0; i < 4; ++i)
        #pragma unroll
        for (int j = 0; j < 2; ++j)
            acc[i][j] = (float4v){0.f, 0.f, 0.f, 0.f};

    const int zrow = t >> 1;
    const int ch   = t & 1;
    int gz = node0 + zrow; if (gz > n - 1) gz = n - 1;
    const _Float16* zsrc = zh + (size_t)gz * 128 + ch * 16;

    for (int kt = 0; kt < 4; ++kt) {
        __syncthreads();
        *(half8*)&zs[zrow * 40 + ch * 16]     = *(const half8*)(zsrc + kt * 32);
        *(half8*)&zs[zrow * 40 + ch * 16 + 8] = *(const half8*)(zsrc + kt * 32 + 8);
        __syncthreads();

        half8 af[4], bf[2];
        #pragma unroll
        for (int mi = 0; mi < 4; ++mi)
            af[mi] = *(const half8*)&zs[(wrow + mi * 16 + lrow) * 40 + lk * 8];
        #pragma unroll
        for (int ni = 0; ni < 2; ++ni)
            bf[ni] = *(const half8*)&wd1s[(wcol + ni * 16 + lrow) * 136 + kt * 32 + lk * 8];

        #pragma unroll
        for (int mi = 0; mi < 4; ++mi)
            #pragma unroll
            for (int ni = 0; ni < 2; ++ni)
                acc[mi][ni] = __builtin_amdgcn_mfma_f32_16x16x32_f16(
                    af[mi], bf[ni], acc[mi][ni], 0, 0, 0);
    }

    #pragma unroll
    for (int mi = 0; mi < 4; ++mi) {
        #pragma unroll
        for (int ni = 0; ni < 2; ++ni) {
            #pragma unroll
            for (int r = 0; r < 4; ++r) {
                int rr = wrow + mi * 16 + lk * 4 + r;
                int cc = wcol + ni * 16 + lrow;
                float v = fmaxf(acc[mi][ni][r] + bd1s[cc], 0.f);
                dsd[rr * 66 + cc] = (_Float16)v;
            }
        }
    }
    __syncthreads();

    if (t < 128) {
        int node = node0 + t;
        if (node < n) {
            float lg[10];
            #pragma unroll
            for (int c = 0; c < 10; ++c) lg[c] = bd2s[c];
            #pragma unroll
            for (int k8 = 0; k8 < 8; ++k8) {
                half8 dv = *(const half8*)&dsd[t * 66 + k8 * 8];
                #pragma unroll
                for (int j = 0; j < 8; ++j) {
                    float dj = (float)dv[j];
                    #pragma unroll
                    for (int c = 0; c < 10; ++c)
                        lg[c] += dj * wd2s[(k8 * 8 + j) * 10 + c];
                }
            }
            float mx = lg[0];
            #pragma unroll
            for (int c = 1; c < 10; ++c) mx = fmaxf(mx, lg[c]);
            float ssum = 0.f;
            #pragma unroll
            for (int c = 0; c < 10; ++c) { lg[c] = expf(lg[c] - mx); ssum += lg[c]; }
            float inv = 1.f / ssum;
            #pragma unroll
            for (int c = 0; c < 10; ++c)
                out[(size_t)node * 10 + c] = lg[c] * inv;
        }
    }
}

// ---------------------------------------------------------------------------
// CSR scan
// ---------------------------------------------------------------------------
__global__ __launch_bounds__(256)
void block_sum_kernel(const int* __restrict__ cnt, int* __restrict__ bsum, int n)
{
    __shared__ int sh[256];
    int t = threadIdx.x;
    int i = blockIdx.x * 256 + t;
    sh[t] = (i < n) ? cnt[i] : 0;
    __syncthreads();
    #pragma unroll
    for (int off = 128; off > 0; off >>= 1) {
        if (t < off) sh[t] += sh[t + off];
        __syncthreads();
    }
    if (t == 0) bsum[blockIdx.x] = sh[0];
}

__global__ __launch_bounds__(256)
void scan_bsum_kernel(int* __restrict__ bsum, int* __restrict__ row_start, int nb, int n)
{
    __shared__ int sh[256];
    int t = threadIdx.x;
    int v = (t < nb) ? bsum[t] : 0;
    sh[t] = v;
    __syncthreads();
    #pragma unroll
    for (int off = 1; off < 256; off <<= 1) {
        int xv = (t >= off) ? sh[t - off] : 0;
        __syncthreads();
        sh[t] += xv;
        __syncthreads();
    }
    if (t < nb) bsum[t] = sh[t] - v;
    if (t == 255) row_start[n] = sh[255];
}

__global__ __launch_bounds__(256)
void scan_final_kernel(const int* __restrict__ cnt, const int* __restrict__ boff,
                       int* __restrict__ row_start, int n)
{
    __shared__ int sh[256];
    int t = threadIdx.x;
    int i = blockIdx.x * 256 + t;
    int v = (i < n) ? cnt[i] : 0;
    sh[t] = v;
    __syncthreads();
    #pragma unroll
    for (int off = 1; off < 256; off <<= 1) {
        int xv = (t >= off) ? sh[t - off] : 0;
        __syncthreads();
        sh[t] += xv;
        __syncthreads();
    }
    if (i < n) row_start[i] = boff[blockIdx.x] + sh[t] - v;
}

// ---------------------------------------------------------------------------
// Fused GATv2: one wave per dst node; 4x16-lane groups, 4 edges in flight.
// Packed-f16 message math + fdot2 logit; defer-max online softmax (THR=8).
// ---------------------------------------------------------------------------
__global__ __launch_bounds__(256)
void gat_aggregate_kernel(const _Float16* __restrict__ xlr, const int2* __restrict__ recs,
                          const float* __restrict__ We, const float* __restrict__ att,
                          const float* __restrict__ bg, const int* __restrict__ row_start,
                          _Float16* __restrict__ z, int n)
{
    const int wave = threadIdx.x >> 6;
    const int lane = threadIdx.x & 63;
    const int node = blockIdx.x * 4 + wave;
    if (node >= n) return;

    const int g  = lane >> 4;
    const int sl = lane & 15;
    const int d0 = sl * 8;

    half2v at_h[4], we_h[4], xr_h[4];
    {
        float4 a0 = *(const float4*)(att + d0);
        float4 a1 = *(const float4*)(att + d0 + 4);
        float4 w0 = *(const float4*)(We + d0);
        float4 w1 = *(const float4*)(We + d0 + 4);
        at_h[0] = (half2v){(_Float16)a0.x, (_Float16)a0.y};
        at_h[1] = (half2v){(_Float16)a0.z, (_Float16)a0.w};
        at_h[2] = (half2v){(_Float16)a1.x, (_Float16)a1.y};
        at_h[3] = (half2v){(_Float16)a1.z, (_Float16)a1.w};
        we_h[0] = (half2v){(_Float16)w0.x, (_Float16)w0.y};
        we_h[1] = (half2v){(_Float16)w0.z, (_Float16)w0.w};
        we_h[2] = (half2v){(_Float16)w1.x, (_Float16)w1.y};
        we_h[3] = (half2v){(_Float16)w1.z, (_Float16)w1.w};
        half8 xh = *(const half8*)(xlr + (size_t)node * 256 + 128 + d0);
        #pragma unroll
        for (int q = 0; q < 4; ++q)
            xr_h[q] = (half2v){xh[2 * q], xh[2 * q + 1]};
    }
    const half2v slope2 = (half2v){(_Float16)NEG_SLOPE, (_Float16)NEG_SLOPE};

    const int beg = row_start[node];
    const int end = row_start[node + 1];

    float m_run = -INFINITY;
    float l_run = 0.f;
    float acc[8];
    #pragma unroll
    for (int j = 0; j < 8; ++j) acc[j] = 0.f;

    for (int idx = beg + g; idx < end; idx += 4) {
        int2 rec = recs[idx];
        _Float16 eh = (_Float16)__int_as_float(rec.y);
        half2v e2 = (half2v){eh, eh};
        half8 xh = *(const half8*)(xlr + (size_t)rec.x * 256 + d0);

        float part = 0.f;
        #pragma unroll
        for (int q = 0; q < 4; ++q) {
            half2v xq = (half2v){xh[2 * q], xh[2 * q + 1]};
            half2v mq = xq + (e2 * we_h[q] + xr_h[q]);
            half2v lq = __builtin_elementwise_max(mq, mq * slope2);
#if __has_builtin(__builtin_amdgcn_fdot2)
            part = __builtin_amdgcn_fdot2(lq, at_h[q], part, false);
#else
            part += (float)lq.x * (float)at_h[q].x + (float)lq.y * (float)at_h[q].y;
#endif
        }
        part += __shfl_xor(part, 1);
        part += __shfl_xor(part, 2);
        part += __shfl_xor(part, 4);
        part += __shfl_xor(part, 8);

        if (part <= m_run + 8.f) {
            float p = __expf(part - m_run);
            l_run += p;
            #pragma unroll
            for (int j = 0; j < 8; ++j) acc[j] += p * (float)xh[j];
        } else {
            float sc = __expf(m_run - part);
            l_run = l_run * sc + 1.f;
            #pragma unroll
            for (int j = 0; j < 8; ++j) acc[j] = acc[j] * sc + (float)xh[j];
            m_run = part;
        }
    }

    #pragma unroll
    for (int off = 16; off <= 32; off <<= 1) {
        float m_o = __shfl_xor(m_run, off);
        float l_o = __shfl_xor(l_run, off);
        float mn  = fmaxf(m_run, m_o);
        float sa  = (m_run == mn) ? 1.f : __expf(m_run - mn);
        float sb  = (m_o   == mn) ? 1.f : __expf(m_o - mn);
        l_run = l_run * sa + l_o * sb;
        #pragma unroll
        for (int j = 0; j < 8; ++j) {
            float a_o = __shfl_xor(acc[j], off);
            acc[j] = acc[j] * sa + a_o * sb;
        }
        m_run = mn;
    }

    if (g == 0) {
        float inv = (l_run > 0.f) ? 1.f / l_run : 0.f;
        const float* bgp = bg + d0;
        half8 o;
        #pragma unroll
        for (int j = 0; j < 8; ++j) {
            float v = fmaxf(acc[j] * inv + bgp[j], 0.f);
            o[j] = (_Float16)v;
        }
        *(half8*)(z + (size_t)node * 128 + d0) = o;
    }
}

// ---------------------------------------------------------------------------
// Launch
// ---------------------------------------------------------------------------
extern "C" void kernel_launch(void* const* d_in, const int* in_sizes, int n_in,
                              void* d_out, int out_size, void* d_ws, size_t ws_size,
                              hipStream_t stream)
{
    const float* x    = (const float*)d_in[0];
    const float* pos  = (const float*)d_in[1];
    const int*   ei   = (const int*)d_in[2];
    const float* ea   = (const float*)d_in[3];
    const float* W1   = (const float*)d_in[4];
    const float* b1   = (const float*)d_in[5];
    const float* W2   = (const float*)d_in[6];
    const float* b2   = (const float*)d_in[7];
    const float* W3   = (const float*)d_in[8];
    const float* b3   = (const float*)d_in[9];
    const float* Wl   = (const float*)d_in[10];
    const float* bl   = (const float*)d_in[11];
    const float* Wr   = (const float*)d_in[12];
    const float* br   = (const float*)d_in[13];
    const float* We   = (const float*)d_in[14];
    const float* att  = (const float*)d_in[15];
    const float* bg   = (const float*)d_in[16];
    const float* Wd1  = (const float*)d_in[17];
    const float* bd1  = (const float*)d_in[18];
    const float* Wd2  = (const float*)d_in[19];
    const float* bd2  = (const float*)d_in[20];
    float* out = (float*)d_out;

    const int N = in_sizes[0] / 500;   // 50000
    const int E = in_sizes[2] / 2;     // 800000

    // ---- workspace layout (bytes) ----
    char* base = (char*)d_ws;
    const size_t szR = (size_t)N * 512 * 2;   // 51.2 MB region size
    _Float16* A0h = (_Float16*)(base);                            // N*512 f16
    _Float16* h2h = (_Float16*)(base);                            // N*256 f16 (A0h dead)
    _Float16* zh  = (_Float16*)(base + (size_t)N * 384 * 2);      // N*128 f16
    char* r1 = base + szR;
    _Float16* h1h = (_Float16*)(r1);                              // N*512 f16
    _Float16* xlr = (_Float16*)(r1);                              // N*256 f16 (h1h dead)
    char* r2 = base + 2 * szR;
    _Float16* W1t   = (_Float16*)(r2);                // 512*512
    _Float16* W2t   = W1t  + 512 * 512;               // 256*512
    _Float16* Wct   = W2t  + 256 * 512;               // 256*256 (folded W3@[Wl|Wr])
    _Float16* Wd1t  = Wct  + 256 * 256;               // 64*128
    float*    bcombo = (float*)(Wd1t + 64 * 128);     // 256 f32
    int* cnt       = (int*)(r2 + 2 * 1024 * 1024);
    int* row_start = cnt + N;
    int* bsum      = row_start + N + 1;
    int2* recs     = (int2*)(r2 + 3 * 1024 * 1024);   // E * 8 bytes
    int* rank      = (int*)(recs + E);                // E ints

    const int* srcArr = ei;
    const int* dstArr = ei + E;
    const int gx = (N + 127) / 128;                   // 391 row-blocks
    const int nb = (N + 255) / 256;                   // 196
    const int eb = (E + 255) / 256;                   // 3125

    // ---- fused prep: concat + weight converts + folds + edge count+rank ----
    hipMemsetAsync(cnt, 0, (size_t)N * sizeof(int), stream);
    prep_mega_kernel<<<2697 + eb, 256, 0, stream>>>(
        x, pos, A0h, W1, W1t, W2, W2t, Wd1, Wd1t,
        W3, Wl, Wr, Wct, b3, bl, br, bcombo, dstArr, cnt, rank, N, E);

    // ---- CSR scan ----
    block_sum_kernel<<<nb, 256, 0, stream>>>(cnt, bsum, N);
    scan_bsum_kernel<<<1, 256, 0, stream>>>(bsum, row_start, nb, N);
    scan_final_kernel<<<nb, 256, 0, stream>>>(cnt, bsum, row_start, N);

    // ---- GEMM1; each block also scatters ~512 edges (atomic-free) ----
    gemm_f16_kernel<0,1,1><<<gx * 4, 256, 0, stream>>>(
        A0h, W1t, b1, nullptr, h1h, N, 512, 512, 4, 1,
        dstArr, srcArr, ea, row_start, rank, recs, E);
    gemm_f16_kernel<0,1,0><<<gx * 2, 256, 0, stream>>>(
        h1h, W2t, b2, nullptr, h2h, N, 256, 512, 2, 1,
        nullptr, nullptr, nullptr, nullptr, nullptr, nullptr, 0);
    // ---- folded h->xl|xr transform: xlr = h2 @ Wcombo + bcombo ----
    gemm_f16_kernel<0,1,0><<<gx * 2, 256, 0, stream>>>(
        h2h, Wct, bcombo, nullptr, xlr, N, 256, 256, 2, 0,
        nullptr, nullptr, nullptr, nullptr, nullptr, nullptr, 0);

    // ---- fused GATv2 softmax + aggregation ----
    gat_aggregate_kernel<<<(N + 3) / 4, 256, 0, stream>>>(xlr, recs, We, att, bg,
                                                          row_start, zh, N);

    // ---- fused decoder (dec1 + dec2 + softmax) ----
    dec_fused_kernel<<<gx, 256, 0, stream>>>(zh, Wd1t, bd1, Wd2, bd2, out, N);
}